// Round 7
// baseline (132.021 us; speedup 1.0000x reference)
//
#include <hip/hip_runtime.h>
#include <hip/hip_bf16.h>
#include <math.h>

#define NN 512

// smearing constants
#define START 0.006737946999085467f            // exp(-5)
#define STEP  ((1.0f - START) * (1.0f/15.0f))  // linspace step
#define SB    (0.125f * (1.0f - START))
#define BETA  (1.0f/(SB*SB))
#define LOG2E 1.4426950408889634f
#define NB    (-(BETA)*LOG2E)                  // exp(-beta t^2) = exp2(NB t^2)

// ===========================================================================
// R7: fully fused per-stage kernels. One block per i-row (grid 512, 256 thr =
// 16 j-slots x 16 c-lanes), 32 j-tiles of 16. Per tile: geometry+smearing G
// into LDS (1 exp2/thread), contract with DIRECT global kk/qq loads (issued
// before the barrier to overlap the G-phase), acc[6|9] regs only. In-block
// shfl+LDS reduce feeds the MLP epilogue inline -- no partials buffers, no
// b-kernels, 2 launches total. Fill re-poison (~80 us/iter) is harness floor.
// ===========================================================================

// ---------------------------------------------------------------------------
// k1: stage-1 einsums -> att1 -> silu(W1) -> att2 row.  Grid 512.
// ---------------------------------------------------------------------------
__global__ __launch_bounds__(256) void k1(const float* __restrict__ x,
                                          const float* __restrict__ W,
                                          const float* __restrict__ W1,
                                          const float* __restrict__ b1,
                                          const float* __restrict__ W2,
                                          float* __restrict__ att2)
{
    const int i   = blockIdx.x;
    const int tid = threadIdx.x;
    const int c   = tid & 15, js = tid >> 4;   // contract role; G role: gj=c, gr=js
    const int lane = tid & 63, wv = tid >> 6;

    __shared__ float lG[320];                  // j*20 + r  (pad 20)
    __shared__ float lP[64];                   // j*4 + {d0,d1,d2,pad}
    __shared__ float s_part[4][16][6];
    __shared__ float s_bkq[96];
    __shared__ float s_att[256];
    __shared__ float s_z[16][16];
    __shared__ float s_a1[16];

    const float xi0 = x[i*3+0], xi1 = x[i*3+1], xi2 = x[i*3+2];

    float acc[6] = {0.f,0.f,0.f,0.f,0.f,0.f};  // [kq][b]

    for (int jt = 0; jt < 32; ++jt) {
        const int jb = jt*16;
        __syncthreads();                       // prev tile's lG/lP consumed

        // issue kk/qq loads early (independent of LDS) to overlap G-phase
        const float* Kr = W + (size_t)(jb+js)*256 + c;
        const float* Qr = Kr + NN*256;
        float kk[16], qq[16];
        #pragma unroll
        for (int r = 0; r < 16; ++r) { kk[r] = Kr[r*16]; qq[r] = Qr[r*16]; }

        // ---- G phase: thread (gj=c, gr=js) -> one exp2 ----
        {
            float d0 = xi0 - x[(jb+c)*3+0];
            float d1 = xi1 - x[(jb+c)*3+1];
            float d2 = xi2 - x[(jb+c)*3+2];
            float nsq = fmaf(d0,d0, fmaf(d1,d1, fmaf(d2,d2, 1e-6f)));
            float rs  = __builtin_amdgcn_rsqf(nsq);
            float nrm = nsq * rs;
            float inv = rs * rs;
            float cutv = 0.f;
            if (nrm < 5.0f) cutv = 0.5f*(__cosf(nrm*0.6283185307179586f)+1.0f);
            float en = exp2f(-LOG2E * nrm);
            if (js == 0) {
                float4 dP; dP.x = d0*inv; dP.y = d1*inv; dP.z = d2*inv; dP.w = 0.f;
                *reinterpret_cast<float4*>(&lP[c*4]) = dP;
            }
            float t = en - (START + STEP*(float)js);
            lG[c*20 + js] = cutv * exp2f(NB*t*t);
        }
        __syncthreads();

        // ---- contract: thread (c, js) handles j = jb+js ----
        const float4* gp = reinterpret_cast<const float4*>(&lG[js*20]);
        float4 gA = gp[0], gB = gp[1], gC = gp[2], gD = gp[3];
        float tk = 0.f, tq = 0.f;
        tk = fmaf(gA.x,kk[ 0], tk); tq = fmaf(gA.x,qq[ 0], tq);
        tk = fmaf(gA.y,kk[ 1], tk); tq = fmaf(gA.y,qq[ 1], tq);
        tk = fmaf(gA.z,kk[ 2], tk); tq = fmaf(gA.z,qq[ 2], tq);
        tk = fmaf(gA.w,kk[ 3], tk); tq = fmaf(gA.w,qq[ 3], tq);
        tk = fmaf(gB.x,kk[ 4], tk); tq = fmaf(gB.x,qq[ 4], tq);
        tk = fmaf(gB.y,kk[ 5], tk); tq = fmaf(gB.y,qq[ 5], tq);
        tk = fmaf(gB.z,kk[ 6], tk); tq = fmaf(gB.z,qq[ 6], tq);
        tk = fmaf(gB.w,kk[ 7], tk); tq = fmaf(gB.w,qq[ 7], tq);
        tk = fmaf(gC.x,kk[ 8], tk); tq = fmaf(gC.x,qq[ 8], tq);
        tk = fmaf(gC.y,kk[ 9], tk); tq = fmaf(gC.y,qq[ 9], tq);
        tk = fmaf(gC.z,kk[10], tk); tq = fmaf(gC.z,qq[10], tq);
        tk = fmaf(gC.w,kk[11], tk); tq = fmaf(gC.w,qq[11], tq);
        tk = fmaf(gD.x,kk[12], tk); tq = fmaf(gD.x,qq[12], tq);
        tk = fmaf(gD.y,kk[13], tk); tq = fmaf(gD.y,qq[13], tq);
        tk = fmaf(gD.z,kk[14], tk); tq = fmaf(gD.z,qq[14], tq);
        tk = fmaf(gD.w,kk[15], tk); tq = fmaf(gD.w,qq[15], tq);
        float4 dd = *reinterpret_cast<const float4*>(&lP[js*4]);
        acc[0] = fmaf(tk, dd.x, acc[0]);
        acc[1] = fmaf(tk, dd.y, acc[1]);
        acc[2] = fmaf(tk, dd.z, acc[2]);
        acc[3] = fmaf(tq, dd.x, acc[3]);
        acc[4] = fmaf(tq, dd.y, acc[4]);
        acc[5] = fmaf(tq, dd.z, acc[5]);
    }

    // ---- reduce over 16 js (lane bits 4,5 + wave) ----
    #pragma unroll
    for (int v = 0; v < 6; ++v) {
        float t = acc[v];
        t += __shfl_xor(t, 16);
        t += __shfl_xor(t, 32);
        if (lane < 16) s_part[wv][c][v] = t;
    }
    __syncthreads();

    if (tid < 96) {                            // s_bkq[kq*48 + b*16 + c]
        int kq = tid / 48, rem = tid - kq*48;
        int b = rem >> 4, c2 = rem & 15;
        int f = kq*3 + b;
        s_bkq[tid] = s_part[0][c2][f] + s_part[1][c2][f]
                   + s_part[2][c2][f] + s_part[3][c2][f];
    }
    __syncthreads();

    {                                          // att1[h,g]
        int h = tid >> 4, g = tid & 15;
        s_att[tid] = s_bkq[     h]*s_bkq[48+     g]
                   + s_bkq[16 + h]*s_bkq[48+16 + g]
                   + s_bkq[32 + h]*s_bkq[48+32 + g];
    }
    __syncthreads();

    {                                          // z = att1 @ W1.T (split 16-seg)
        int h = tid & 15, seg = tid >> 4;
        const float* w1 = W1 + h*256 + seg*16;
        const float* a  = s_att + seg*16;
        float p = 0.f;
        #pragma unroll
        for (int k = 0; k < 16; ++k) p = fmaf(a[k], w1[k], p);
        s_z[seg][h] = p;
    }
    __syncthreads();

    if (tid < 16) {
        float z = b1[tid];
        #pragma unroll
        for (int seg = 0; seg < 16; ++seg) z += s_z[seg][tid];
        s_a1[tid] = z / (1.0f + __expf(-z));
    }
    __syncthreads();

    float a1[16];
    #pragma unroll
    for (int cc = 0; cc < 16; ++cc) a1[cc] = s_a1[cc];
    #pragma unroll
    for (int p = 0; p < 4; ++p) {
        int o = tid + p*256;
        const float4* w2 = reinterpret_cast<const float4*>(W2 + o*16);
        float4 wa = w2[0], wb = w2[1], wc = w2[2], wd = w2[3];
        float accv = wa.x*a1[0] + wa.y*a1[1] + wa.z*a1[2] + wa.w*a1[3]
                   + wb.x*a1[4] + wb.y*a1[5] + wb.z*a1[6] + wb.w*a1[7]
                   + wc.x*a1[8] + wc.y*a1[9] + wc.z*a1[10]+ wc.w*a1[11]
                   + wd.x*a1[12]+ wd.y*a1[13]+ wd.z*a1[14]+ wd.w*a1[15];
        att2[i*1024 + o] = accv;
    }
}

// ---------------------------------------------------------------------------
// k2: stage-3 right-term + S + separable left-term -> att3 -> silu(W3) -> out.
// ---------------------------------------------------------------------------
__global__ __launch_bounds__(256) void k2(const float* __restrict__ x,
                                          const float* __restrict__ att2,
                                          const float* __restrict__ W3,
                                          const float* __restrict__ b3,
                                          const float* __restrict__ W4,
                                          const float* __restrict__ b4,
                                          float* __restrict__ out)
{
    const int i   = blockIdx.x;
    const int tid = threadIdx.x;
    const int c   = tid & 15, js = tid >> 4;
    const int lane = tid & 63, wv = tid >> 6;

    __shared__ float lG[320];
    __shared__ float lP[64];
    __shared__ float s_part[4][16][9];
    __shared__ float s_red[144];
    __shared__ float s_att[256];
    __shared__ float s_z[16][16];
    __shared__ float s_a1[16];

    const float xi0 = x[i*3+0], xi1 = x[i*3+1], xi2 = x[i*3+2];

    float acc[9] = {0.f,0.f,0.f,0.f,0.f,0.f,0.f,0.f,0.f};  // 6 main + 3 S (r=c)

    for (int jt = 0; jt < 32; ++jt) {
        const int jb = jt*16;
        __syncthreads();

        const float* Rk = att2 + (size_t)(jb+js)*1024 + 512 + c;
        const float* Rq = Rk + 256;
        float kk[16], qq[16];
        #pragma unroll
        for (int r = 0; r < 16; ++r) { kk[r] = Rk[r*16]; qq[r] = Rq[r*16]; }

        {
            float d0 = xi0 - x[(jb+c)*3+0];
            float d1 = xi1 - x[(jb+c)*3+1];
            float d2 = xi2 - x[(jb+c)*3+2];
            float nsq = fmaf(d0,d0, fmaf(d1,d1, fmaf(d2,d2, 1e-6f)));
            float rs  = __builtin_amdgcn_rsqf(nsq);
            float nrm = nsq * rs;
            float inv = rs * rs;
            float cutv = 0.f;
            if (nrm < 5.0f) cutv = 0.5f*(__cosf(nrm*0.6283185307179586f)+1.0f);
            float en = exp2f(-LOG2E * nrm);
            if (js == 0) {
                float4 dP; dP.x = d0*inv; dP.y = d1*inv; dP.z = d2*inv; dP.w = 0.f;
                *reinterpret_cast<float4*>(&lP[c*4]) = dP;
            }
            float t = en - (START + STEP*(float)js);
            lG[c*20 + js] = cutv * exp2f(NB*t*t);
        }
        __syncthreads();

        const float4* gp = reinterpret_cast<const float4*>(&lG[js*20]);
        float4 gA = gp[0], gB = gp[1], gC = gp[2], gD = gp[3];
        float tk = 0.f, tq = 0.f;
        tk = fmaf(gA.x,kk[ 0], tk); tq = fmaf(gA.x,qq[ 0], tq);
        tk = fmaf(gA.y,kk[ 1], tk); tq = fmaf(gA.y,qq[ 1], tq);
        tk = fmaf(gA.z,kk[ 2], tk); tq = fmaf(gA.z,qq[ 2], tq);
        tk = fmaf(gA.w,kk[ 3], tk); tq = fmaf(gA.w,qq[ 3], tq);
        tk = fmaf(gB.x,kk[ 4], tk); tq = fmaf(gB.x,qq[ 4], tq);
        tk = fmaf(gB.y,kk[ 5], tk); tq = fmaf(gB.y,qq[ 5], tq);
        tk = fmaf(gB.z,kk[ 6], tk); tq = fmaf(gB.z,qq[ 6], tq);
        tk = fmaf(gB.w,kk[ 7], tk); tq = fmaf(gB.w,qq[ 7], tq);
        tk = fmaf(gC.x,kk[ 8], tk); tq = fmaf(gC.x,qq[ 8], tq);
        tk = fmaf(gC.y,kk[ 9], tk); tq = fmaf(gC.y,qq[ 9], tq);
        tk = fmaf(gC.z,kk[10], tk); tq = fmaf(gC.z,qq[10], tq);
        tk = fmaf(gC.w,kk[11], tk); tq = fmaf(gC.w,qq[11], tq);
        tk = fmaf(gD.x,kk[12], tk); tq = fmaf(gD.x,qq[12], tq);
        tk = fmaf(gD.y,kk[13], tk); tq = fmaf(gD.y,qq[13], tq);
        tk = fmaf(gD.z,kk[14], tk); tq = fmaf(gD.z,qq[14], tq);
        tk = fmaf(gD.w,kk[15], tk); tq = fmaf(gD.w,qq[15], tq);
        float4 dd = *reinterpret_cast<const float4*>(&lP[js*4]);
        acc[0] = fmaf(tk, dd.x, acc[0]);
        acc[1] = fmaf(tk, dd.y, acc[1]);
        acc[2] = fmaf(tk, dd.z, acc[2]);
        acc[3] = fmaf(tq, dd.x, acc[3]);
        acc[4] = fmaf(tq, dd.y, acc[4]);
        acc[5] = fmaf(tq, dd.z, acc[5]);
        float gc = lG[js*20 + c];              // this lane's r=c for S
        acc[6] = fmaf(gc, dd.x, acc[6]);
        acc[7] = fmaf(gc, dd.y, acc[7]);
        acc[8] = fmaf(gc, dd.z, acc[8]);
    }

    #pragma unroll
    for (int v = 0; v < 9; ++v) {
        float t = acc[v];
        t += __shfl_xor(t, 16);
        t += __shfl_xor(t, 32);
        if (lane < 16) s_part[wv][c][v] = t;
    }
    __syncthreads();

    if (tid < 144) {                           // s_red: 96 bkq + 48 S
        int o = tid;
        float s;
        if (o < 96) {
            int kq = o / 48, rem = o - kq*48;
            int b = rem >> 4, c2 = rem & 15;
            int f = kq*3 + b;
            s = s_part[0][c2][f] + s_part[1][c2][f]
              + s_part[2][c2][f] + s_part[3][c2][f];
        } else {
            int oS = o - 96;
            int r = oS / 3, b = oS - r*3;
            int f = 6 + b;
            s = s_part[0][r][f] + s_part[1][r][f]
              + s_part[2][r][f] + s_part[3][r][f];
        }
        s_red[o] = s;
    }
    __syncthreads();

    if (tid < 96) {                            // left-term via S
        int kq = tid / 48, rem = tid - kq*48;
        int b = rem >> 4, cc = rem & 15;
        const float* lrow = att2 + i*1024 + kq*256 + cc;
        float add = 0.f;
        #pragma unroll
        for (int r = 0; r < 16; ++r)
            add = fmaf(lrow[r*16], s_red[96 + r*3 + b], add);
        s_red[tid] += add;
    }
    __syncthreads();

    {
        int h = tid >> 4, g = tid & 15;
        s_att[tid] = s_red[     h]*s_red[48+     g]
                   + s_red[16 + h]*s_red[48+16 + g]
                   + s_red[32 + h]*s_red[48+32 + g];
    }
    __syncthreads();

    {
        int h = tid & 15, seg = tid >> 4;
        const float* w3 = W3 + h*256 + seg*16;
        const float* a  = s_att + seg*16;
        float p = 0.f;
        #pragma unroll
        for (int k = 0; k < 16; ++k) p = fmaf(a[k], w3[k], p);
        s_z[seg][h] = p;
    }
    __syncthreads();

    if (tid < 16) {
        float z = b3[tid];
        #pragma unroll
        for (int seg = 0; seg < 16; ++seg) z += s_z[seg][tid];
        s_a1[tid] = z / (1.0f + __expf(-z));
    }
    __syncthreads();

    if (tid == 0) {
        float accv = b4[0];
        #pragma unroll
        for (int cc = 0; cc < 16; ++cc) accv = fmaf(s_a1[cc], W4[cc], accv);
        out[i] = accv;
    }
}

extern "C" void kernel_launch(void* const* d_in, const int* in_sizes, int n_in,
                              void* d_out, int out_size, void* d_ws, size_t ws_size,
                              hipStream_t stream) {
    (void)in_sizes; (void)n_in; (void)out_size; (void)ws_size;
    const float* x  = (const float*)d_in[0];
    const float* W  = (const float*)d_in[1];
    const float* W1 = (const float*)d_in[2];
    const float* b1 = (const float*)d_in[3];
    const float* W2 = (const float*)d_in[4];
    const float* W3 = (const float*)d_in[5];
    const float* b3 = (const float*)d_in[6];
    const float* W4 = (const float*)d_in[7];
    const float* b4 = (const float*)d_in[8];

    float* att2 = (float*)d_ws;             // 512*1024 f32 = 2 MB
    float* out  = (float*)d_out;

    k1<<<512, 256, 0, stream>>>(x, W, W1, b1, W2, att2);
    k2<<<512, 256, 0, stream>>>(x, att2, W3, b3, W4, b4, out);
}